// Round 4
// baseline (580.536 us; speedup 1.0000x reference)
//
#include <hip/hip_runtime.h>
#include <hip/hip_bf16.h>

#define T_STEPS 2048
#define BATCH 16
#define DIM 1024
#define NDIM 64
#define M_TOTAL (T_STEPS * BATCH)  // 32768
#define STRIDE (BATCH * NDIM)      // floats per timestep in Kp/Qp = 1024
#define CH 32                      // recurrence chunk (timesteps per LDS buffer)

typedef __attribute__((ext_vector_type(8))) short bf16x8;
typedef __attribute__((ext_vector_type(4))) float f32x4;
typedef __attribute__((ext_vector_type(2))) float f32x2;

#define NEG_LOG2E -1.44269504088896f

__device__ inline unsigned pk_bf(float lo, float hi) {
    __hip_bfloat162 h = __float22bfloat162_rn(float2{lo, hi});
    return *(unsigned*)&h;  // v_cvt_pk_bf16_f32
}

template <int CTRL>
__device__ inline float dpp_add(float x) {
    int v = __builtin_amdgcn_update_dpp(0, __float_as_int(x), CTRL, 0xF, 0xF, true);
    return x + __int_as_float(v);
}
// full sum across contiguous 16-lane rows (result in all 16 lanes)
__device__ inline float red16(float x) {
    x = dpp_add<0xB1>(x);   // quad_perm xor1
    x = dpp_add<0x4E>(x);   // quad_perm xor2
    x = dpp_add<0x141>(x);  // row_half_mirror (xor4)
    x = dpp_add<0x140>(x);  // row_mirror (xor8)
    return x;
}
// four independent 16-lane reductions, stage-interleaved: 4 DPP chains overlap,
// and the 3-instruction gaps satisfy the VALU->DPP hazard without s_nops.
__device__ inline void red16x4(float& a, float& b, float& cc, float& d) {
    a = dpp_add<0xB1>(a);  b = dpp_add<0xB1>(b);  cc = dpp_add<0xB1>(cc);  d = dpp_add<0xB1>(d);
    a = dpp_add<0x4E>(a);  b = dpp_add<0x4E>(b);  cc = dpp_add<0x4E>(cc);  d = dpp_add<0x4E>(d);
    a = dpp_add<0x141>(a); b = dpp_add<0x141>(b); cc = dpp_add<0x141>(cc); d = dpp_add<0x141>(d);
    a = dpp_add<0x140>(a); b = dpp_add<0x140>(b); cc = dpp_add<0x140>(cc); d = dpp_add<0x140>(d);
}

#define AS1 __attribute__((address_space(1)))
#define AS3 __attribute__((address_space(3)))
__device__ inline void gl_lds16(const float* g, float* l) {
    __builtin_amdgcn_global_load_lds((const AS1 unsigned*)g, (AS3 unsigned*)l, 16, 0, 0);
}
__device__ inline void gl_lds16s(const unsigned short* g, unsigned short* l) {
    __builtin_amdgcn_global_load_lds((const AS1 unsigned*)g, (AS3 unsigned*)l, 16, 0, 0);
}
__device__ inline void gl_lds4(const float* g, float* l) {
    __builtin_amdgcn_global_load_lds((const AS1 unsigned*)g, (AS3 unsigned*)l, 4, 0, 0);
}
#define WAIT_VM0 do { __builtin_amdgcn_s_waitcnt(0x0F70); asm volatile("" ::: "memory"); } while (0)

// ---------------- W prepack: fp32 -> bf16, row order [K, Q, V, A] ----------------
__global__ __launch_bounds__(256) void pack_w(
    const float* __restrict__ Wk, const float* __restrict__ Wq,
    const float* __restrict__ Wv, const float* __restrict__ Wa,
    unsigned short* __restrict__ Wb) {
    int n = blockIdx.x;  // 0..255
    int sel = n >> 6;
    const float* W = (sel == 0) ? Wk : (sel == 1) ? Wq : (sel == 2) ? Wv : Wa;
    int k4 = threadIdx.x * 4;
    float4 f = *(const float4*)(W + (size_t)(n & 63) * DIM + k4);
    uint2 u;
    u.x = pk_bf(f.x, f.y);
    u.y = pk_bf(f.z, f.w);
    *(uint2*)(Wb + (size_t)n * DIM + k4) = u;
}

// ---------------- projection: m97-style 128x128 tile, global_load_lds staging ----------------
__global__ __launch_bounds__(256, 2) void proj_kernel(
    const float* __restrict__ x, const unsigned short* __restrict__ Wb,
    const float* __restrict__ ba, float* __restrict__ Kp, float* __restrict__ Qp,
    float* __restrict__ VAi) {
    __shared__ float sA[128 * 64];            // 32 KB fp32
    __shared__ unsigned short sB[128 * 64];   // 16 KB bf16

    const int m0 = blockIdx.x * 128;
    const int ntile = blockIdx.y;
    const int tid = threadIdx.x;
    const int wv = tid >> 6, lane = tid & 63, lrow = lane & 15, quad = lane >> 4;
    const int wm = wv & 1, wn = wv >> 1;   // wave = (m-half, n-half) of 128x128 tile

    f32x4 acc[4][4];
#pragma unroll
    for (int a = 0; a < 4; a++)
#pragma unroll
        for (int b = 0; b < 4; b++) acc[a][b] = (f32x4)(0.f);

    const float* xg = x + (size_t)(m0 + (tid >> 4)) * DIM + (tid & 15) * 4;
    const unsigned short* wg = Wb + (size_t)(ntile * 128 + (tid >> 3)) * DIM + (tid & 7) * 8;

    for (int it = 0; it < 16; ++it) {
        const int k0 = it * 64;
        __syncthreads();  // previous iteration's frag reads done
#pragma unroll
        for (int j = 0; j < 8; ++j)  // A: 128x64 fp32 = 32 KB
            gl_lds16(xg + (size_t)(16 * j) * DIM + k0, &sA[(tid + 256 * j) * 4]);
#pragma unroll
        for (int j = 0; j < 4; ++j)  // B: 128x64 bf16 = 16 KB
            gl_lds16s(wg + (size_t)(32 * j) * DIM + k0, &sB[(tid + 256 * j) * 8]);
        WAIT_VM0;
        __syncthreads();

#pragma unroll
        for (int ks = 0; ks < 2; ++ks) {
            bf16x8 af[4];
#pragma unroll
            for (int mt = 0; mt < 4; ++mt) {
                const float* pa = &sA[(wm * 64 + mt * 16 + lrow) * 64 + ks * 32 + quad * 8];
                float4 lo = ((const float4*)pa)[0], hi = ((const float4*)pa)[1];
                unsigned pk[4] = {pk_bf(lo.x, lo.y), pk_bf(lo.z, lo.w),
                                  pk_bf(hi.x, hi.y), pk_bf(hi.z, hi.w)};
                af[mt] = *(bf16x8*)pk;
            }
#pragma unroll
            for (int nt = 0; nt < 4; ++nt) {
                bf16x8 bfr = *(const bf16x8*)&sB[(wn * 64 + nt * 16 + lrow) * 64 + ks * 32 + quad * 8];
#pragma unroll
                for (int mt = 0; mt < 4; ++mt)
                    acc[mt][nt] = __builtin_amdgcn_mfma_f32_16x16x32_bf16(af[mt], bfr, acc[mt][nt], 0, 0, 0);
            }
        }
    }

    // epilogue: C/D layout col = lane&15, row = quad*4 + reg  [m89-verified]
    const int g2 = ntile * 2 + wn;  // 0=K 1=Q 2=V 3=A
    float bav[4];
    if (g2 == 3) {
#pragma unroll
        for (int nt = 0; nt < 4; ++nt) bav[nt] = ba[nt * 16 + lrow];
    }
#pragma unroll
    for (int mt = 0; mt < 4; ++mt)
#pragma unroll
        for (int nt = 0; nt < 4; ++nt) {
            int col = nt * 16 + lrow;
#pragma unroll
            for (int reg = 0; reg < 4; ++reg) {
                int m = m0 + wm * 64 + mt * 16 + quad * 4 + reg;
                float vvv = acc[mt][nt][reg];
                if (g2 == 0) Kp[(size_t)m * 64 + col] = vvv;
                else if (g2 == 1) Qp[(size_t)m * 64 + col] = vvv;
                else if (g2 == 2) VAi[(size_t)m * 128 + col * 2] = vvv;
                else VAi[(size_t)m * 128 + col * 2 + 1] = NEG_LOG2E * (vvv + bav[nt]);
            }
        }
}

// ---------------- kq[m] = K[m,:] . Q[m,:] ----------------
__global__ __launch_bounds__(256) void kq_kernel(
    const float* __restrict__ Kp, const float* __restrict__ Qp, float* __restrict__ kq) {
    int m = blockIdx.x * 16 + (threadIdx.x >> 4);
    int c = threadIdx.x & 15;
    float4 k = *(const float4*)(Kp + (size_t)m * 64 + c * 4);
    float4 q = *(const float4*)(Qp + (size_t)m * 64 + c * 4);
    float p = k.x * q.x + k.y * q.y + k.z * q.z + k.w * q.w;
    p = red16(p);
    if (c == 0) kq[m] = p;
}

// ---------------- elementwise silu epilogue: out = o*o*sigmoid(o) ----------------
__global__ __launch_bounds__(256) void silu_kernel(float* __restrict__ out) {
    size_t idx = ((size_t)blockIdx.x * 256 + threadIdx.x) * 4;
    f32x4 o = *(const f32x4*)(out + idx);
    f32x4 rr;
#pragma unroll
    for (int j = 0; j < 4; ++j) {
        float e = __builtin_amdgcn_exp2f(o[j] * NEG_LOG2E);
        rr[j] = o[j] * o[j] * __builtin_amdgcn_rcpf(1.f + e);
    }
    *(f32x4*)(out + idx) = rr;
}

// ---------------- recurrence: TWO row-groups per wave ----------------
// grid (8 g-pairs, 16 batches) x 64; wave handles g (=bx) and g+8 for batch b.
// K/Q/kq streams depend only on (t, b) -> shared LDS + shared slot registers.
// THEORY (R4): per-step stall (~220 cy) is serial-chain latency (DPP reduction +
// exp2/rcp transcendentals) that reordering can't shrink. Two independent
// recurrences in one wave overlap their chains: wall/step = max(chain, issue).
__global__ __launch_bounds__(64, 1) void recur_kernel(
    const float* __restrict__ Kp, const float* __restrict__ Qp,
    const float* __restrict__ VAi, const float* __restrict__ KQp,
    const float* __restrict__ S0, const float* __restrict__ d_alpha,
    float* __restrict__ out, float* __restrict__ Sout) {
    __shared__ float Kl[2][CH][64];    // 16 KB (shared by both problems)
    __shared__ float Ql[2][CH][64];    // 16 KB
    __shared__ float VAlA[2][CH][8];   // 2 KB (rows gA*4..+3)
    __shared__ float VAlB[2][CH][8];   // 2 KB (rows gB*4..+3)
    __shared__ float KQl[2][64];       // 0.5 KB (only [0..31] used per buffer)
    __shared__ float OlA[CH][4];       // per-chunk output staging
    __shared__ float OlB[CH][4];

    int b = blockIdx.y, gA = blockIdx.x, gB = gA + 8, lane = threadIdx.x;
    int r = lane >> 4, c = lane & 15, c4 = c * 4;
    int iA = gA * 4 + r, iB = gB * 4 + r;

    f32x4 sA = *(const f32x4*)(S0 + ((size_t)b * NDIM + iA) * NDIM + c4);
    f32x4 sB_ = *(const f32x4*)(S0 + ((size_t)b * NDIM + iB) * NDIM + c4);
    f32x2 sA01 = sA.lo, sA23 = sA.hi, sB01 = sB_.lo, sB23 = sB_.hi;
    float daA2 = d_alpha[iA] * NEG_LOG2E;
    float daB2 = d_alpha[iB] * NEG_LOG2E;

    const float* Kbase = Kp + (size_t)b * NDIM + (size_t)(lane >> 4) * STRIDE + (lane & 15) * 4;
    const float* Qbase = Qp + (size_t)b * NDIM + (size_t)(lane >> 4) * STRIDE + (lane & 15) * 4;
    const float* VAbaseA = VAi + (size_t)b * 128 + gA * 8 + (lane & 1) * 4 + (size_t)(lane >> 1) * 2048;
    const float* VAbaseB = VAi + (size_t)b * 128 + gB * 8 + (lane & 1) * 4 + (size_t)(lane >> 1) * 2048;
    const float* KQbase = KQp + b + (size_t)(lane & 31) * BATCH;

    auto load_chunk = [&](int t0, int buf) {
#pragma unroll
        for (int j = 0; j < 8; ++j) {
            gl_lds16(Kbase + (size_t)(t0 + j * 4) * STRIDE, &Kl[buf][j * 4][0]);
            gl_lds16(Qbase + (size_t)(t0 + j * 4) * STRIDE, &Ql[buf][j * 4][0]);
        }
        gl_lds16(VAbaseA + (size_t)t0 * 2048, &VAlA[buf][0][0]);
        gl_lds16(VAbaseB + (size_t)t0 * 2048, &VAlB[buf][0][0]);
        gl_lds4(KQbase + (size_t)t0 * BATCH, &KQl[buf][0]);
    };

    load_chunk(0, 0);
    WAIT_VM0;

    // register slot pipeline: slot sl=t&1 holds (k,q,kq | vaA,vaB) for step t;
    // at step t the freed slot is refilled with index t+2. Dead loads at t=30,31
    // read in-block LDS garbage and are overwritten by the post-chunk refill.
    f32x2 k01[2], k23[2], q01[2], q23[2], vaA[2], vaB[2];
    float kqv[2];
    {
        const float* Kb0 = &Kl[0][0][0] + c4;
        const float* Qb0 = &Ql[0][0][0] + c4;
#pragma unroll
        for (int u = 0; u < 2; ++u) {
            f32x4 kk_ = *(const f32x4*)(Kb0 + u * 64);
            f32x4 qq_ = *(const f32x4*)(Qb0 + u * 64);
            k01[u] = kk_.lo; k23[u] = kk_.hi;
            q01[u] = qq_.lo; q23[u] = qq_.hi;
            vaA[u] = *(const f32x2*)&VAlA[0][u][r * 2];
            vaB[u] = *(const f32x2*)&VAlB[0][u][r * 2];
            kqv[u] = KQl[0][u];
        }
    }

#define STEP(u, sl) do {                                                        \
    f32x2 k0v = k01[sl], k1v = k23[sl], q0v = q01[sl], q1v = q23[sl];           \
    f32x2 vvaA = vaA[sl], vvaB = vaB[sl];                                       \
    float kqs = kqv[sl];                                                        \
    f32x4 kk_ = *(const f32x4*)(Kt + (u + 2) * 64);                             \
    f32x4 qq_ = *(const f32x4*)(Qt + (u + 2) * 64);                             \
    k01[sl] = kk_.lo; k23[sl] = kk_.hi;                                         \
    q01[sl] = qq_.lo; q23[sl] = qq_.hi;                                         \
    vaA[sl] = *(const f32x2*)(VtA + (u + 2) * 8);                               \
    vaB[sl] = *(const f32x2*)(VtB + (u + 2) * 8);                               \
    kqv[sl] = Qk[t4 + u + 2];                                                   \
    f32x2 pkA = k0v * sA01; pkA = k1v * sA23 + pkA;                             \
    f32x2 pqA = q0v * sA01; pqA = q1v * sA23 + pqA;                             \
    f32x2 pkB = k0v * sB01; pkB = k1v * sB23 + pkB;                             \
    f32x2 pqB = q0v * sB01; pqB = q1v * sB23 + pqB;                             \
    float rkA = pkA.x + pkA.y, rqA = pqA.x + pqA.y;                             \
    float rkB = pkB.x + pkB.y, rqB = pqB.x + pqB.y;                             \
    red16x4(rkA, rqA, rkB, rqB);                                                \
    float vA_ = vvaA.x, vB_ = vvaB.x;                                           \
    f32x2 wA01 = vA_ * k0v, wA23 = vA_ * k1v;                                   \
    f32x2 wB01 = vB_ * k0v, wB23 = vB_ * k1v;                                   \
    f32x2 dA01 = sA01 - wA01, dA23 = sA23 - wA23;                               \
    f32x2 dB01 = sB01 - wB01, dB23 = sB23 - wB23;                               \
    float alA = __builtin_amdgcn_rcpf(                                          \
        1.f + __builtin_amdgcn_exp2f(fmaf(daA2, rkA, vvaA.y)));                 \
    float alB = __builtin_amdgcn_rcpf(                                          \
        1.f + __builtin_amdgcn_exp2f(fmaf(daB2, rkB, vvaB.y)));                 \
    f32x2 aA = {alA, alA}, aB = {alB, alB};                                     \
    sA01 = wA01 + aA * dA01;                                                    \
    sA23 = wA23 + aA * dA23;                                                    \
    sB01 = wB01 + aB * dB01;                                                    \
    sB23 = wB23 + aB * dB23;                                                    \
    float vkqA = vA_ * kqs, vkqB = vB_ * kqs;                                   \
    float oA = fmaf(alA, rqA - vkqA, vkqA);  /* S_t.q_t */                      \
    float oB = fmaf(alB, rqB - vkqB, vkqB);                                     \
    if (c == 0) { OlA[t4 + u][r] = oA; OlB[t4 + u][r] = oB; }                   \
} while (0)

#pragma unroll 1
    for (int j = 0; j < T_STEPS / CH; ++j) {
        const int cb = j & 1, nb = cb ^ 1;
        if (j + 1 < T_STEPS / CH) load_chunk((j + 1) * CH, nb);

        const float* Kb = &Kl[cb][0][0] + c4;
        const float* Qb = &Ql[cb][0][0] + c4;
        const float* VbA = &VAlA[cb][0][0] + r * 2;
        const float* VbB = &VAlB[cb][0][0] + r * 2;
        const float* Qk = &KQl[cb][0];

#pragma unroll 1
        for (int t4 = 0; t4 < CH; t4 += 4) {   // rolled hot body
            const float* Kt = Kb + t4 * 64;
            const float* Qt = Qb + t4 * 64;
            const float* VtA = VbA + t4 * 8;
            const float* VtB = VbB + t4 * 8;
            STEP(0, 0);
            STEP(1, 1);
            STEP(2, 0);
            STEP(3, 1);
        }
        WAIT_VM0;  // next-chunk staging (issued a whole chunk ago) has landed

        if (lane < 32) {  // dump chunk outputs: lane = local t, 4 rows as float4
            float4 tA = *(const float4*)&OlA[lane][0];
            float4 tB = *(const float4*)&OlB[lane][0];
            float* ob = out + ((size_t)(j * CH + lane) * BATCH + b) * NDIM;
            *(float4*)(ob + gA * 4) = tA;
            *(float4*)(ob + gB * 4) = tB;
        }

        if (j + 1 < T_STEPS / CH) {  // refill slot pipeline from next buffer
            const float* Kn = &Kl[nb][0][0] + c4;
            const float* Qn = &Ql[nb][0][0] + c4;
#pragma unroll
            for (int u = 0; u < 2; ++u) {
                f32x4 kk_ = *(const f32x4*)(Kn + u * 64);
                f32x4 qq_ = *(const f32x4*)(Qn + u * 64);
                k01[u] = kk_.lo; k23[u] = kk_.hi;
                q01[u] = qq_.lo; q23[u] = qq_.hi;
                vaA[u] = *(const f32x2*)&VAlA[nb][u][r * 2];
                vaB[u] = *(const f32x2*)&VAlB[nb][u][r * 2];
                kqv[u] = KQl[nb][u];
            }
        }
    }
#undef STEP

    *(float4*)(Sout + ((size_t)b * NDIM + iA) * NDIM + c4) =
        float4{sA01.x, sA01.y, sA23.x, sA23.y};
    *(float4*)(Sout + ((size_t)b * NDIM + iB) * NDIM + c4) =
        float4{sB01.x, sB01.y, sB23.x, sB23.y};
}

extern "C" void kernel_launch(void* const* d_in, const int* in_sizes, int n_in,
                              void* d_out, int out_size, void* d_ws, size_t ws_size,
                              hipStream_t stream) {
    const float* x  = (const float*)d_in[0];
    const float* S0 = (const float*)d_in[1];
    const float* Wk = (const float*)d_in[2];
    const float* Wv = (const float*)d_in[3];
    const float* Wq = (const float*)d_in[4];
    const float* Wa = (const float*)d_in[5];
    const float* da = (const float*)d_in[6];
    const float* ba = (const float*)d_in[7];

    float* out = (float*)d_out;
    float* Sout = out + (size_t)T_STEPS * BATCH * NDIM;

    const size_t per = (size_t)M_TOTAL * NDIM;
    float* Kp  = (float*)d_ws;           // per floats
    float* Qp  = Kp + per;               // per
    float* VAi = Qp + per;               // 2*per (v,a interleaved per row)
    float* kq  = VAi + 2 * per;          // M_TOTAL
    unsigned short* Wb = (unsigned short*)(kq + M_TOTAL);  // 512 KB bf16

    pack_w<<<dim3(256), dim3(256), 0, stream>>>(Wk, Wq, Wv, Wa, Wb);
    proj_kernel<<<dim3(M_TOTAL / 128, 2), dim3(256), 0, stream>>>(x, Wb, ba, Kp, Qp, VAi);
    kq_kernel<<<dim3(M_TOTAL / 16), dim3(256), 0, stream>>>(Kp, Qp, kq);
    recur_kernel<<<dim3(8, BATCH), dim3(64), 0, stream>>>(Kp, Qp, VAi, kq, S0, da, out, Sout);
    silu_kernel<<<dim3((T_STEPS * BATCH * NDIM) / (256 * 4)), dim3(256), 0, stream>>>(out);
}

// Round 5
// 451.193 us; speedup vs baseline: 1.2867x; 1.2867x over previous
//
#include <hip/hip_runtime.h>
#include <hip/hip_bf16.h>

#define T_STEPS 2048
#define BATCH 16
#define DIM 1024
#define NDIM 64
#define M_TOTAL (T_STEPS * BATCH)  // 32768
#define STRIDE (BATCH * NDIM)      // floats per timestep in Kp/Qp = 1024
#define CH 32                      // recurrence chunk (timesteps per LDS buffer)

typedef __attribute__((ext_vector_type(8))) short bf16x8;
typedef __attribute__((ext_vector_type(4))) float f32x4;
typedef __attribute__((ext_vector_type(2))) float f32x2;

#define NEG_LOG2E -1.44269504088896f

__device__ inline unsigned pk_bf(float lo, float hi) {
    __hip_bfloat162 h = __float22bfloat162_rn(float2{lo, hi});
    return *(unsigned*)&h;  // v_cvt_pk_bf16_f32
}

template <int CTRL>
__device__ inline float dpp_add(float x) {
    int v = __builtin_amdgcn_update_dpp(0, __float_as_int(x), CTRL, 0xF, 0xF, true);
    return x + __int_as_float(v);
}
// full sum across contiguous 16-lane rows (result in all 16 lanes)
__device__ inline float red16(float x) {
    x = dpp_add<0xB1>(x);   // quad_perm xor1
    x = dpp_add<0x4E>(x);   // quad_perm xor2
    x = dpp_add<0x141>(x);  // row_half_mirror (xor4)
    x = dpp_add<0x140>(x);  // row_mirror (xor8)
    return x;
}
// two independent 16-lane reductions, stage-interleaved so their DPP chains overlap
__device__ inline void red16x2(float& a, float& b) {
    a = dpp_add<0xB1>(a);  b = dpp_add<0xB1>(b);
    a = dpp_add<0x4E>(a);  b = dpp_add<0x4E>(b);
    a = dpp_add<0x141>(a); b = dpp_add<0x141>(b);
    a = dpp_add<0x140>(a); b = dpp_add<0x140>(b);
}
__device__ inline float dot4(f32x4 a, f32x4 b) {
    f32x2 t = a.lo * b.lo;
    t = a.hi * b.hi + t;
    return t.x + t.y;
}
__device__ inline float silu_o(float o) {  // o * silu(o) = o^2 * sigmoid(o)
    float e = __builtin_amdgcn_exp2f(o * NEG_LOG2E);
    return o * o * __builtin_amdgcn_rcpf(1.f + e);
}

#define AS1 __attribute__((address_space(1)))
#define AS3 __attribute__((address_space(3)))
__device__ inline void gl_lds16(const float* g, float* l) {
    __builtin_amdgcn_global_load_lds((const AS1 unsigned*)g, (AS3 unsigned*)l, 16, 0, 0);
}
__device__ inline void gl_lds4(const float* g, float* l) {
    __builtin_amdgcn_global_load_lds((const AS1 unsigned*)g, (AS3 unsigned*)l, 4, 0, 0);
}
#define WAIT_VM0 do { __builtin_amdgcn_s_waitcnt(0x0F70); asm volatile("" ::: "memory"); } while (0)

// ---------------- projection: 128x128 tile, fp32 staging for x AND W, fused kq ----------------
// grid (256 m-tiles, 2 n-tiles) x 256. n-tile0 = [K|Q] (+ fused kq[m]=K.Q), n-tile1 = [V|A].
// W staged fp32 (L2-resident, 512 KB total), converted to bf16 at frag build like x.
__global__ __launch_bounds__(256, 2) void proj_kernel(
    const float* __restrict__ x,
    const float* __restrict__ Wk, const float* __restrict__ Wq,
    const float* __restrict__ Wv, const float* __restrict__ Wa,
    const float* __restrict__ ba, float* __restrict__ Kp, float* __restrict__ Qp,
    float* __restrict__ VAi, float* __restrict__ kq) {
    __shared__ float sA[128 * 64];    // 32 KB fp32 (x tile)
    __shared__ float sB[128 * 64];    // 32 KB fp32 (W tile)

    const int m0 = blockIdx.x * 128;
    const int ntile = blockIdx.y;
    const int tid = threadIdx.x;
    const int wv = tid >> 6, lane = tid & 63, lrow = lane & 15, quad = lane >> 4;
    const int wm = wv & 1, wn = wv >> 1;   // wave = (m-half, n-half) of 128x128 tile

    const float* w0 = (ntile == 0) ? Wk : Wv;   // tile rows 0..63
    const float* w1 = (ntile == 0) ? Wq : Wa;   // tile rows 64..127

    f32x4 acc[4][4];
#pragma unroll
    for (int a = 0; a < 4; a++)
#pragma unroll
        for (int b = 0; b < 4; b++) acc[a][b] = (f32x4)(0.f);

    // staging bases: lane-contiguous LDS dest (wave-uniform base + lane*16)
    const float* xg = x + (size_t)(m0 + (tid >> 4)) * DIM + (tid & 15) * 4;
    const int wrow = tid >> 4, wcol = (tid & 15) * 4;

    for (int it = 0; it < 16; ++it) {
        const int k0 = it * 64;
        __syncthreads();  // previous iteration's frag reads done
#pragma unroll
        for (int j = 0; j < 8; ++j)  // x: 128x64 fp32 = 32 KB
            gl_lds16(xg + (size_t)(16 * j) * DIM + k0, &sA[(tid + 256 * j) * 4]);
#pragma unroll
        for (int j = 0; j < 4; ++j)  // W rows 0..63
            gl_lds16(w0 + (size_t)(16 * j + wrow) * DIM + k0 + wcol, &sB[(tid + 256 * j) * 4]);
#pragma unroll
        for (int j = 0; j < 4; ++j)  // W rows 64..127
            gl_lds16(w1 + (size_t)(16 * j + wrow) * DIM + k0 + wcol, &sB[(tid + 256 * (j + 4)) * 4]);
        WAIT_VM0;
        __syncthreads();

#pragma unroll
        for (int ks = 0; ks < 2; ++ks) {
            bf16x8 af[4];
#pragma unroll
            for (int mt = 0; mt < 4; ++mt) {
                const float* pa = &sA[(wm * 64 + mt * 16 + lrow) * 64 + ks * 32 + quad * 8];
                float4 lo = ((const float4*)pa)[0], hi = ((const float4*)pa)[1];
                unsigned pk[4] = {pk_bf(lo.x, lo.y), pk_bf(lo.z, lo.w),
                                  pk_bf(hi.x, hi.y), pk_bf(hi.z, hi.w)};
                af[mt] = *(bf16x8*)pk;
            }
#pragma unroll
            for (int nt = 0; nt < 4; ++nt) {
                const float* pb = &sB[(wn * 64 + nt * 16 + lrow) * 64 + ks * 32 + quad * 8];
                float4 lo = ((const float4*)pb)[0], hi = ((const float4*)pb)[1];
                unsigned pk[4] = {pk_bf(lo.x, lo.y), pk_bf(lo.z, lo.w),
                                  pk_bf(hi.x, hi.y), pk_bf(hi.z, hi.w)};
                bf16x8 bfr = *(bf16x8*)pk;
#pragma unroll
                for (int mt = 0; mt < 4; ++mt)
                    acc[mt][nt] = __builtin_amdgcn_mfma_f32_16x16x32_bf16(af[mt], bfr, acc[mt][nt], 0, 0, 0);
            }
        }
    }

    // epilogue: C/D layout col = lane&15, row = quad*4 + reg  [m89-verified]
    const int g2 = ntile * 2 + wn;  // 0=K 1=Q 2=V 3=A
    float bav[4];
    if (g2 == 3) {
#pragma unroll
        for (int nt = 0; nt < 4; ++nt) bav[nt] = ba[nt * 16 + lrow];
    }
#pragma unroll
    for (int mt = 0; mt < 4; ++mt)
#pragma unroll
        for (int nt = 0; nt < 4; ++nt) {
            int col = nt * 16 + lrow;
#pragma unroll
            for (int reg = 0; reg < 4; ++reg) {
                int m = m0 + wm * 64 + mt * 16 + quad * 4 + reg;
                float vvv = acc[mt][nt][reg];
                if (g2 == 0) Kp[(size_t)m * 64 + col] = vvv;
                else if (g2 == 1) Qp[(size_t)m * 64 + col] = vvv;
                else if (g2 == 2) VAi[(size_t)m * 128 + col * 2] = vvv;
                else VAi[(size_t)m * 128 + col * 2 + 1] = NEG_LOG2E * (vvv + bav[nt]);
            }
        }

    // fused kq[m] = K[m,:].Q[m,:] via LDS restage (ntile-0 blocks only)
    if (ntile == 0) {
        __syncthreads();  // main-loop frag reads done everywhere
        float* dst = (wn == 0) ? sA : sB;   // K tile -> sA, Q tile -> sB, [row][col]
#pragma unroll
        for (int mt = 0; mt < 4; ++mt)
#pragma unroll
            for (int nt = 0; nt < 4; ++nt)
#pragma unroll
                for (int reg = 0; reg < 4; ++reg)
                    dst[(wm * 64 + mt * 16 + quad * 4 + reg) * 64 + nt * 16 + lrow] =
                        acc[mt][nt][reg];
        __syncthreads();
        if (tid < 128) {
            float s = 0.f;
#pragma unroll
            for (int k4 = 0; k4 < 16; ++k4)
                s += dot4(*(const f32x4*)&sA[tid * 64 + k4 * 4],
                          *(const f32x4*)&sB[tid * 64 + k4 * 4]);
            kq[m0 + tid] = s;
        }
    }
}

// ---------------- recurrence ----------------
// grid (16 row-groups, 16 batches) x 64; lane = r*16+c; row i = g*4+r, cols c*4..+3
//
// THEORY (R5): the ~200 cy/step residual stall is lgkmcnt pollution — every prior
// version had ds_reads + an exec-masked ds_write INSIDE each step, forcing per-step
// conservative LDS waits (~120 cy). Fix: 4-step groups with register double-buffer.
// One block of 13 ds_reads per group (one lgkm wait, a full group of slack); the 4
// steps are pure VALU; outputs go to a register quad + one ds_write_b128 per group.
// Silu is applied at the chunk dump (off the hot path).
__global__ __launch_bounds__(64, 1) void recur_kernel(
    const float* __restrict__ Kp, const float* __restrict__ Qp,
    const float* __restrict__ VAi, const float* __restrict__ KQp,
    const float* __restrict__ S0, const float* __restrict__ d_alpha,
    float* __restrict__ out, float* __restrict__ Sout) {
    __shared__ float Kl[2][CH][64];   // 16 KB
    __shared__ float Ql[2][CH][64];   // 16 KB
    __shared__ float VAl[2][CH][8];   // 2 KB: [t] = v0,a0,v1,a1,v2,a2,v3,a3 (rows g*4..+3)
    __shared__ float KQl[2][64];      // 0.5 KB (only [0..31] used per buffer)
    __shared__ float OlT[4][CH];      // transposed output staging: [r][t]

    int b = blockIdx.y, g = blockIdx.x, lane = threadIdx.x;
    int r = lane >> 4, c = lane & 15, i = g * 4 + r, c4 = c * 4;

    f32x4 sv = *(const f32x4*)(S0 + ((size_t)b * NDIM + i) * NDIM + c4);
    float da2 = d_alpha[i] * NEG_LOG2E;  // alpha logit pre-scaled for exp2 form

    const float* Kbase = Kp + (size_t)b * NDIM + (size_t)(lane >> 4) * STRIDE + (lane & 15) * 4;
    const float* Qbase = Qp + (size_t)b * NDIM + (size_t)(lane >> 4) * STRIDE + (lane & 15) * 4;
    const float* VAbase = VAi + (size_t)b * 128 + g * 8 + (lane & 1) * 4 + (size_t)(lane >> 1) * 2048;
    const float* KQbase = KQp + b + (size_t)(lane & 31) * BATCH;

    auto load_chunk = [&](int t0, int buf) {
#pragma unroll
        for (int j = 0; j < 8; ++j) {
            gl_lds16(Kbase + (size_t)(t0 + j * 4) * STRIDE, &Kl[buf][j * 4][0]);
            gl_lds16(Qbase + (size_t)(t0 + j * 4) * STRIDE, &Ql[buf][j * 4][0]);
        }
        gl_lds16(VAbase + (size_t)t0 * 2048, &VAl[buf][0][0]);
        gl_lds4(KQbase + (size_t)t0 * BATCH, &KQl[buf][0]);
    };

    // group register double-buffer: gi = 0/1 (literal everywhere — no dynamic reg indexing)
    f32x4 kg[2][4], qg[2][4], kqg[2];
    f32x2 vg[2][4];
    f32x4 og;

#define LOADG(gi, buf, t4_) do {                                         \
    const float* Kb_ = &Kl[buf][0][0] + (t4_) * 64 + c4;                 \
    const float* Qb_ = &Ql[buf][0][0] + (t4_) * 64 + c4;                 \
    _Pragma("unroll")                                                    \
    for (int u_ = 0; u_ < 4; ++u_) {                                     \
        kg[gi][u_] = *(const f32x4*)(Kb_ + u_ * 64);                     \
        qg[gi][u_] = *(const f32x4*)(Qb_ + u_ * 64);                     \
        vg[gi][u_] = *(const f32x2*)(&VAl[buf][0][0] + ((t4_) + u_) * 8 + r * 2); \
    }                                                                    \
    kqg[gi] = *(const f32x4*)(&KQl[buf][0] + (t4_));                     \
} while (0)

#define STEP(gi, u) do {                                                 \
    f32x4 kv_ = kg[gi][u], qv_ = qg[gi][u];                              \
    f32x2 vva_ = vg[gi][u];                                              \
    float kqs_ = kqg[gi][u];                                             \
    f32x2 pk_ = kv_.lo * sv.lo; pk_ = kv_.hi * sv.hi + pk_;              \
    f32x2 pq_ = qv_.lo * sv.lo; pq_ = qv_.hi * sv.hi + pq_;              \
    float rk_ = pk_.x + pk_.y, rq_ = pq_.x + pq_.y;                      \
    red16x2(rk_, rq_);                                                   \
    float v_ = vva_.x;                                                   \
    f32x4 w_ = v_ * kv_;                                                 \
    f32x4 d_ = sv - w_;                                                  \
    float alpha_ = __builtin_amdgcn_rcpf(                                \
        1.f + __builtin_amdgcn_exp2f(fmaf(da2, rk_, vva_.y)));           \
    sv = w_ + alpha_ * d_;                                               \
    float vkq_ = v_ * kqs_;                                              \
    og[u] = fmaf(alpha_, rq_ - vkq_, vkq_);  /* S_t.q_t */               \
} while (0)

    load_chunk(0, 0);
    WAIT_VM0;
    LOADG(0, 0, 0);

#pragma unroll 1
    for (int j = 0; j < T_STEPS / CH; ++j) {
        const int cb = j & 1, nb = cb ^ 1;
        if (j + 1 < T_STEPS / CH) load_chunk((j + 1) * CH, nb);

#pragma unroll 1
        for (int t8 = 0; t8 < CH; t8 += 8) {
            // group A (regs gi=0): steps t8..t8+3; prefetch gi=1 <- t8+4
            LOADG(1, cb, t8 + 4);
            STEP(0, 0); STEP(0, 1); STEP(0, 2); STEP(0, 3);
            if (c == 0) *(f32x4*)(&OlT[r][t8]) = og;
            // group B (regs gi=1): steps t8+4..t8+7; prefetch gi=0 <- t8+8
            if (t8 + 8 < CH) LOADG(0, cb, t8 + 8);
            STEP(1, 0); STEP(1, 1); STEP(1, 2); STEP(1, 3);
            if (c == 0) *(f32x4*)(&OlT[r][t8 + 4]) = og;
        }
        WAIT_VM0;  // next-chunk staging (issued a whole chunk ago) has landed

        if (lane < 32) {  // dump chunk outputs with fused silu: lane = local t
            float4 t4o;
            t4o.x = silu_o(OlT[0][lane]);
            t4o.y = silu_o(OlT[1][lane]);
            t4o.z = silu_o(OlT[2][lane]);
            t4o.w = silu_o(OlT[3][lane]);
            *(float4*)(out + ((size_t)(j * CH + lane) * BATCH + b) * NDIM + g * 4) = t4o;
        }

        if (j + 1 < T_STEPS / CH) LOADG(0, nb, 0);  // refill pipeline from next buffer
    }
#undef STEP
#undef LOADG

    *(float4*)(Sout + ((size_t)b * NDIM + i) * NDIM + c4) = float4{sv.x, sv.y, sv.z, sv.w};
}

extern "C" void kernel_launch(void* const* d_in, const int* in_sizes, int n_in,
                              void* d_out, int out_size, void* d_ws, size_t ws_size,
                              hipStream_t stream) {
    const float* x  = (const float*)d_in[0];
    const float* S0 = (const float*)d_in[1];
    const float* Wk = (const float*)d_in[2];
    const float* Wv = (const float*)d_in[3];
    const float* Wq = (const float*)d_in[4];
    const float* Wa = (const float*)d_in[5];
    const float* da = (const float*)d_in[6];
    const float* ba = (const float*)d_in[7];

    float* out = (float*)d_out;
    float* Sout = out + (size_t)T_STEPS * BATCH * NDIM;

    const size_t per = (size_t)M_TOTAL * NDIM;
    float* Kp  = (float*)d_ws;           // per floats
    float* Qp  = Kp + per;               // per
    float* VAi = Qp + per;               // 2*per (v,a interleaved per row)
    float* kq  = VAi + 2 * per;          // M_TOTAL

    proj_kernel<<<dim3(M_TOTAL / 128, 2), dim3(256), 0, stream>>>(
        x, Wk, Wq, Wv, Wa, ba, Kp, Qp, VAi, kq);
    recur_kernel<<<dim3(16, BATCH), dim3(64), 0, stream>>>(Kp, Qp, VAi, kq, S0, da, out, Sout);
}

// Round 8
// 446.079 us; speedup vs baseline: 1.3014x; 1.0115x over previous
//
#include <hip/hip_runtime.h>
#include <hip/hip_bf16.h>

#define T_STEPS 2048
#define BATCH 16
#define DIM 1024
#define NDIM 64
#define M_TOTAL (T_STEPS * BATCH)  // 32768
#define STRIDE (BATCH * NDIM)      // floats per timestep in Kp/Qp = 1024
#define CH 32                      // recurrence chunk (timesteps per LDS buffer)
#define NC (T_STEPS / CH)

typedef __attribute__((ext_vector_type(8))) short bf16x8;
typedef __attribute__((ext_vector_type(4))) float f32x4;
typedef __attribute__((ext_vector_type(2))) float f32x2;

#define NEG_LOG2E -1.44269504088896f

__device__ inline unsigned pk_bf(float lo, float hi) {
    __hip_bfloat162 h = __float22bfloat162_rn(float2{lo, hi});
    return *(unsigned*)&h;  // v_cvt_pk_bf16_f32
}

template <int CTRL>
__device__ inline float dpp_add(float x) {
    int v = __builtin_amdgcn_update_dpp(0, __float_as_int(x), CTRL, 0xF, 0xF, true);
    return x + __int_as_float(v);
}
// full sum across contiguous 16-lane rows (result in all 16 lanes)
__device__ inline float red16(float x) {
    x = dpp_add<0xB1>(x);   // quad_perm xor1
    x = dpp_add<0x4E>(x);   // quad_perm xor2
    x = dpp_add<0x141>(x);  // row_half_mirror (xor4)
    x = dpp_add<0x140>(x);  // row_mirror (xor8)
    return x;
}
// two independent 16-lane reductions, stage-interleaved so their DPP chains overlap
__device__ inline void red16x2(float& a, float& b) {
    a = dpp_add<0xB1>(a);  b = dpp_add<0xB1>(b);
    a = dpp_add<0x4E>(a);  b = dpp_add<0x4E>(b);
    a = dpp_add<0x141>(a); b = dpp_add<0x141>(b);
    a = dpp_add<0x140>(a); b = dpp_add<0x140>(b);
}
__device__ inline float silu_o(float o) {  // o * silu(o) = o^2 * sigmoid(o)
    float e = __builtin_amdgcn_exp2f(o * NEG_LOG2E);
    return o * o * __builtin_amdgcn_rcpf(1.f + e);
}

#define AS1 __attribute__((address_space(1)))
#define AS3 __attribute__((address_space(3)))
__device__ inline void gl_lds16(const float* g, float* l) {
    __builtin_amdgcn_global_load_lds((const AS1 unsigned*)g, (AS3 unsigned*)l, 16, 0, 0);
}
__device__ inline void gl_lds16s(const unsigned short* g, unsigned short* l) {
    __builtin_amdgcn_global_load_lds((const AS1 unsigned*)g, (AS3 unsigned*)l, 16, 0, 0);
}
__device__ inline void gl_lds4(const float* g, float* l) {
    __builtin_amdgcn_global_load_lds((const AS1 unsigned*)g, (AS3 unsigned*)l, 4, 0, 0);
}
#define WAIT_VM0 do { __builtin_amdgcn_s_waitcnt(0x0F70); asm volatile("" ::: "memory"); } while (0)

// ---------------- W prepack: fp32 -> bf16, row order [K, Q, V, A] ----------------
__global__ __launch_bounds__(256) void pack_w(
    const float* __restrict__ Wk, const float* __restrict__ Wq,
    const float* __restrict__ Wv, const float* __restrict__ Wa,
    unsigned short* __restrict__ Wb) {
    int n = blockIdx.x;  // 0..255
    int sel = n >> 6;
    const float* W = (sel == 0) ? Wk : (sel == 1) ? Wq : (sel == 2) ? Wv : Wa;
    int k4 = threadIdx.x * 4;
    float4 f = *(const float4*)(W + (size_t)(n & 63) * DIM + k4);
    uint2 u;
    u.x = pk_bf(f.x, f.y);
    u.y = pk_bf(f.z, f.w);
    *(uint2*)(Wb + (size_t)n * DIM + k4) = u;
}

// ---------------- projection: m97-style 128x128 tile, global_load_lds staging ----------------
__global__ __launch_bounds__(256, 2) void proj_kernel(
    const float* __restrict__ x, const unsigned short* __restrict__ Wb,
    const float* __restrict__ ba, float* __restrict__ Kp, float* __restrict__ Qp,
    float* __restrict__ VAi) {
    __shared__ float sA[128 * 64];            // 32 KB fp32
    __shared__ unsigned short sB[128 * 64];   // 16 KB bf16

    const int m0 = blockIdx.x * 128;
    const int ntile = blockIdx.y;
    const int tid = threadIdx.x;
    const int wv = tid >> 6, lane = tid & 63, lrow = lane & 15, quad = lane >> 4;
    const int wm = wv & 1, wn = wv >> 1;   // wave = (m-half, n-half) of 128x128 tile

    f32x4 acc[4][4];
#pragma unroll
    for (int a = 0; a < 4; a++)
#pragma unroll
        for (int b = 0; b < 4; b++) acc[a][b] = (f32x4)(0.f);

    const float* xg = x + (size_t)(m0 + (tid >> 4)) * DIM + (tid & 15) * 4;
    const unsigned short* wg = Wb + (size_t)(ntile * 128 + (tid >> 3)) * DIM + (tid & 7) * 8;

    for (int it = 0; it < 16; ++it) {
        const int k0 = it * 64;
        __syncthreads();  // previous iteration's frag reads done
#pragma unroll
        for (int j = 0; j < 8; ++j)  // A: 128x64 fp32 = 32 KB
            gl_lds16(xg + (size_t)(16 * j) * DIM + k0, &sA[(tid + 256 * j) * 4]);
#pragma unroll
        for (int j = 0; j < 4; ++j)  // B: 128x64 bf16 = 16 KB
            gl_lds16s(wg + (size_t)(32 * j) * DIM + k0, &sB[(tid + 256 * j) * 8]);
        WAIT_VM0;
        __syncthreads();

#pragma unroll
        for (int ks = 0; ks < 2; ++ks) {
            bf16x8 af[4];
#pragma unroll
            for (int mt = 0; mt < 4; ++mt) {
                const float* pa = &sA[(wm * 64 + mt * 16 + lrow) * 64 + ks * 32 + quad * 8];
                float4 lo = ((const float4*)pa)[0], hi = ((const float4*)pa)[1];
                unsigned pk[4] = {pk_bf(lo.x, lo.y), pk_bf(lo.z, lo.w),
                                  pk_bf(hi.x, hi.y), pk_bf(hi.z, hi.w)};
                af[mt] = *(bf16x8*)pk;
            }
#pragma unroll
            for (int nt = 0; nt < 4; ++nt) {
                bf16x8 bfr = *(const bf16x8*)&sB[(wn * 64 + nt * 16 + lrow) * 64 + ks * 32 + quad * 8];
#pragma unroll
                for (int mt = 0; mt < 4; ++mt)
                    acc[mt][nt] = __builtin_amdgcn_mfma_f32_16x16x32_bf16(af[mt], bfr, acc[mt][nt], 0, 0, 0);
            }
        }
    }

    // epilogue: C/D layout col = lane&15, row = quad*4 + reg  [m89-verified]
    const int g2 = ntile * 2 + wn;  // 0=K 1=Q 2=V 3=A
    float bav[4];
    if (g2 == 3) {
#pragma unroll
        for (int nt = 0; nt < 4; ++nt) bav[nt] = ba[nt * 16 + lrow];
    }
#pragma unroll
    for (int mt = 0; mt < 4; ++mt)
#pragma unroll
        for (int nt = 0; nt < 4; ++nt) {
            int col = nt * 16 + lrow;
#pragma unroll
            for (int reg = 0; reg < 4; ++reg) {
                int m = m0 + wm * 64 + mt * 16 + quad * 4 + reg;
                float vvv = acc[mt][nt][reg];
                if (g2 == 0) Kp[(size_t)m * 64 + col] = vvv;
                else if (g2 == 1) Qp[(size_t)m * 64 + col] = vvv;
                else if (g2 == 2) VAi[(size_t)m * 128 + col * 2] = vvv;
                else VAi[(size_t)m * 128 + col * 2 + 1] = NEG_LOG2E * (vvv + bav[nt]);
            }
        }
}

// ---------------- kq[m] = K[m,:].Q[m,:]   kk[m] = K[m,:].K[m+B,:]  (k_t . k_{t+1}) ----------------
__global__ __launch_bounds__(256) void kq_kernel(
    const float* __restrict__ Kp, const float* __restrict__ Qp,
    float* __restrict__ kq, float* __restrict__ kk) {
    int m = blockIdx.x * 16 + (threadIdx.x >> 4);
    int c = threadIdx.x & 15;
    float4 k = *(const float4*)(Kp + (size_t)m * 64 + c * 4);
    float4 q = *(const float4*)(Qp + (size_t)m * 64 + c * 4);
    float4 kn = {0.f, 0.f, 0.f, 0.f};
    if (m + BATCH < M_TOTAL) kn = *(const float4*)(Kp + (size_t)(m + BATCH) * 64 + c * 4);
    float pq = k.x * q.x + k.y * q.y + k.z * q.z + k.w * q.w;
    float pk = k.x * kn.x + k.y * kn.y + k.z * kn.z + k.w * kn.w;
    red16x2(pq, pk);
    if (c == 0) { kq[m] = pq; kk[m] = pk; }
}

// ---------------- recurrence ----------------
// grid (16 row-groups, 16 batches) x 64; lane = r*16+c; row i = g*4+r, cols c*4..+3
//
// R5 (confirmed): group-batched LDS loads + pure-VALU steps removed the lgkm stalls.
// R6/R7: option-A look-ahead ON TOP of the group structure — every high-latency unit
// (DPP reduction, exp2, rcp) produces for a consumer a full step away:
//   alpha_t = rcp(1 + ee),      ee = exp2(z_t) computed at step t-1
//   rk_{t+1} = fma(alpha_t, ck - v*kk, v*kk),  kk = k_t.k_{t+1} precomputed,
//   ck = S_{t-1}.k_{t+1}, rq = S_{t-1}.q_t     via red16x2 at step t-1 (full-step slack)
// Loop-carried chain: rcp -> fma -> fma -> exp2 (~60 cy) < issue (~150 cy) -> issue-bound.
// (R7: STEP look-ahead operands passed explicitly per call site — no in-macro
//  bank-selection ternaries; semantics identical to R6.)
__global__ __launch_bounds__(64, 1) void recur_kernel(
    const float* __restrict__ Kp, const float* __restrict__ Qp,
    const float* __restrict__ VAi, const float* __restrict__ KQp,
    const float* __restrict__ KKp,
    const float* __restrict__ S0, const float* __restrict__ d_alpha,
    float* __restrict__ out, float* __restrict__ Sout) {
    __shared__ float Kl[2][CH][64];   // 16 KB
    __shared__ float Ql[2][CH][64];   // 16 KB
    __shared__ float VAl[2][CH][8];   // 2 KB: [t] = v0,a0,v1,a1,v2,a2,v3,a3 (rows g*4..+3)
    __shared__ float KQl[2][64];      // 0.5 KB (only [0..31] used per buffer)
    __shared__ float KKl[2][64];      // 0.5 KB
    __shared__ float OlT[4][CH];      // transposed output staging: [r][t]

    int b = blockIdx.y, g = blockIdx.x, lane = threadIdx.x;
    int r = lane >> 4, c = lane & 15, i = g * 4 + r, c4 = c * 4;

    f32x4 sv = *(const f32x4*)(S0 + ((size_t)b * NDIM + i) * NDIM + c4);
    float da2 = d_alpha[i] * NEG_LOG2E;  // alpha logit pre-scaled for exp2 form

    const float* Kbase = Kp + (size_t)b * NDIM + (size_t)(lane >> 4) * STRIDE + (lane & 15) * 4;
    const float* Qbase = Qp + (size_t)b * NDIM + (size_t)(lane >> 4) * STRIDE + (lane & 15) * 4;
    const float* VAbase = VAi + (size_t)b * 128 + g * 8 + (lane & 1) * 4 + (size_t)(lane >> 1) * 2048;
    const float* KQbase = KQp + b + (size_t)(lane & 31) * BATCH;
    const float* KKbase = KKp + b + (size_t)(lane & 31) * BATCH;

    auto load_chunk = [&](int t0, int buf) {
#pragma unroll
        for (int j = 0; j < 8; ++j) {
            gl_lds16(Kbase + (size_t)(t0 + j * 4) * STRIDE, &Kl[buf][j * 4][0]);
            gl_lds16(Qbase + (size_t)(t0 + j * 4) * STRIDE, &Ql[buf][j * 4][0]);
        }
        gl_lds16(VAbase + (size_t)t0 * 2048, &VAl[buf][0][0]);
        gl_lds4(KQbase + (size_t)t0 * BATCH, &KQl[buf][0]);
        gl_lds4(KKbase + (size_t)t0 * BATCH, &KKl[buf][0]);
    };

    // group register double-buffer (banks 0/1, all indices literal after expansion)
    f32x4 kg[2][4], qg[2][4], kqg[2], kkg[2];
    f32x2 vg[2][4];
    f32x4 og;
    float ee, ckm, rqm, vkk, vkq, v_cur;

#define LOADG(gi, buf, t4_) do {                                          \
    const float* Kb_ = &Kl[buf][0][0] + (t4_) * 64 + c4;                  \
    const float* Qb_ = &Ql[buf][0][0] + (t4_) * 64 + c4;                  \
    _Pragma("unroll")                                                     \
    for (int u_ = 0; u_ < 4; ++u_) {                                      \
        kg[gi][u_] = *(const f32x4*)(Kb_ + u_ * 64);                      \
        qg[gi][u_] = *(const f32x4*)(Qb_ + u_ * 64);                      \
        vg[gi][u_] = *(const f32x2*)(&VAl[buf][0][0] + ((t4_) + u_) * 8 + r * 2); \
    }                                                                     \
    kqg[gi] = *(const f32x4*)(&KQl[buf][0] + (t4_));                      \
    kkg[gi] = *(const f32x4*)(&KKl[buf][0] + (t4_));                      \
} while (0)

// STEP for step t: kt_ = k_t, kt2_ = k_{t+2}, (qt1_,vt1_,kqt1_,kkt1_) = step-(t+1) inputs.
// All operands named explicitly at the call site — no bank-selection inside the macro.
#define STEP(u, kt_, kt2_, qt1_, vt1_, kqt1_, kkt1_) do {                 \
    float alpha_ = __builtin_amdgcn_rcpf(1.f + ee);                       \
    float rk1_ = fmaf(alpha_, ckm, vkk);      /* S_t.k_{t+1} */           \
    ee = __builtin_amdgcn_exp2f(fmaf(da2, rk1_, (vt1_).y));               \
    float o_ = fmaf(alpha_, rqm, vkq);        /* S_t.q_t */               \
    f32x4 w_ = v_cur * (kt_);                                             \
    f32x4 d_ = sv - w_;                                                   \
    sv = w_ + alpha_ * d_;                    /* S_t */                   \
    f32x2 pq_ = (qt1_).lo * sv.lo; pq_ = (qt1_).hi * sv.hi + pq_;         \
    f32x2 pk_ = (kt2_).lo * sv.lo; pk_ = (kt2_).hi * sv.hi + pk_;         \
    float rq_ = pq_.x + pq_.y, ck_ = pk_.x + pk_.y;                       \
    red16x2(rq_, ck_);                        /* for step t+1 */          \
    float v1_ = (vt1_).x;                                                 \
    vkq = v1_ * (kqt1_); vkk = v1_ * (kkt1_);                             \
    rqm = rq_ - vkq; ckm = ck_ - vkk;                                     \
    og[u] = o_;                                                           \
    v_cur = v1_;                                                          \
} while (0)

// group of 4 steps with bank A current and bank B holding the next group
#define GROUP_A() do {                                                          \
    STEP(0, kg[0][0], kg[0][2], qg[0][1], vg[0][1], kqg[0][1], kkg[0][1]);      \
    STEP(1, kg[0][1], kg[0][3], qg[0][2], vg[0][2], kqg[0][2], kkg[0][2]);      \
    STEP(2, kg[0][2], kg[1][0], qg[0][3], vg[0][3], kqg[0][3], kkg[0][3]);      \
    STEP(3, kg[0][3], kg[1][1], qg[1][0], vg[1][0], kqg[1][0], kkg[1][0]);      \
} while (0)
#define GROUP_B() do {                                                          \
    STEP(0, kg[1][0], kg[1][2], qg[1][1], vg[1][1], kqg[1][1], kkg[1][1]);      \
    STEP(1, kg[1][1], kg[1][3], qg[1][2], vg[1][2], kqg[1][2], kkg[1][2]);      \
    STEP(2, kg[1][2], kg[0][0], qg[1][3], vg[1][3], kqg[1][3], kkg[1][3]);      \
    STEP(3, kg[1][3], kg[0][1], qg[0][0], vg[0][0], kqg[0][0], kkg[0][0]);      \
} while (0)

    load_chunk(0, 0);
    WAIT_VM0;
    LOADG(0, 0, 0);
    {   // prologue: step-0 inputs from S0
        f32x2 p0 = kg[0][0].lo * sv.lo; p0 = kg[0][0].hi * sv.hi + p0;   // S0.k_0
        f32x2 p1 = qg[0][0].lo * sv.lo; p1 = qg[0][0].hi * sv.hi + p1;   // S0.q_0
        f32x2 p2 = kg[0][1].lo * sv.lo; p2 = kg[0][1].hi * sv.hi + p2;   // S0.k_1
        float rk0 = p0.x + p0.y, rq0 = p1.x + p1.y, ck0 = p2.x + p2.y;
        red16x2(rk0, rq0);
        ck0 = red16(ck0);
        float v0 = vg[0][0].x;
        ee = __builtin_amdgcn_exp2f(fmaf(da2, rk0, vg[0][0].y));
        vkq = v0 * kqg[0][0];
        vkk = v0 * kkg[0][0];
        rqm = rq0 - vkq;
        ckm = ck0 - vkk;
        v_cur = v0;
    }

#pragma unroll 1
    for (int j = 0; j < NC; ++j) {
        const int cb = j & 1, nb = cb ^ 1;
        if (j + 1 < NC) load_chunk((j + 1) * CH, nb);

#pragma unroll 1
        for (int t8 = 0; t8 < 24; t8 += 8) {
            LOADG(1, cb, t8 + 4);
            GROUP_A();
            if (c == 0) *(f32x4*)(&OlT[r][t8]) = og;
            LOADG(0, cb, t8 + 8);
            GROUP_B();
            if (c == 0) *(f32x4*)(&OlT[r][t8 + 4]) = og;
        }
        // last two groups: the final group's look-ahead needs next chunk's group 0
        LOADG(1, cb, 28);
        GROUP_A();
        if (c == 0) *(f32x4*)(&OlT[r][24]) = og;
        WAIT_VM0;            // next-chunk staging (issued a whole chunk ago) landed
        LOADG(0, nb, 0);     // next chunk group 0 (stale-but-initialized on last chunk: dead)
        GROUP_B();
        if (c == 0) *(f32x4*)(&OlT[r][28]) = og;

        if (lane < 32) {  // dump chunk outputs with fused silu: lane = local t
            float4 t4o;
            t4o.x = silu_o(OlT[0][lane]);
            t4o.y = silu_o(OlT[1][lane]);
            t4o.z = silu_o(OlT[2][lane]);
            t4o.w = silu_o(OlT[3][lane]);
            *(float4*)(out + ((size_t)(j * CH + lane) * BATCH + b) * NDIM + g * 4) = t4o;
        }
    }
#undef GROUP_A
#undef GROUP_B
#undef STEP
#undef LOADG

    *(float4*)(Sout + ((size_t)b * NDIM + i) * NDIM + c4) = float4{sv.x, sv.y, sv.z, sv.w};
}

extern "C" void kernel_launch(void* const* d_in, const int* in_sizes, int n_in,
                              void* d_out, int out_size, void* d_ws, size_t ws_size,
                              hipStream_t stream) {
    const float* x  = (const float*)d_in[0];
    const float* S0 = (const float*)d_in[1];
    const float* Wk = (const float*)d_in[2];
    const float* Wv = (const float*)d_in[3];
    const float* Wq = (const float*)d_in[4];
    const float* Wa = (const float*)d_in[5];
    const float* da = (const float*)d_in[6];
    const float* ba = (const float*)d_in[7];

    float* out = (float*)d_out;
    float* Sout = out + (size_t)T_STEPS * BATCH * NDIM;

    const size_t per = (size_t)M_TOTAL * NDIM;
    float* Kp  = (float*)d_ws;           // per floats
    float* Qp  = Kp + per;               // per
    float* VAi = Qp + per;               // 2*per (v,a interleaved per row)
    float* kq  = VAi + 2 * per;          // M_TOTAL
    float* kk  = kq + M_TOTAL;           // M_TOTAL (k_t . k_{t+1})
    unsigned short* Wb = (unsigned short*)(kk + M_TOTAL);  // 512 KB bf16

    pack_w<<<dim3(256), dim3(256), 0, stream>>>(Wk, Wq, Wv, Wa, Wb);
    proj_kernel<<<dim3(M_TOTAL / 128, 2), dim3(256), 0, stream>>>(x, Wb, ba, Kp, Qp, VAi);
    kq_kernel<<<dim3(M_TOTAL / 16), dim3(256), 0, stream>>>(Kp, Qp, kq, kk);
    recur_kernel<<<dim3(16, BATCH), dim3(64), 0, stream>>>(Kp, Qp, VAi, kq, kk, S0, da, out, Sout);
}